// Round 2
// baseline (344.811 us; speedup 1.0000x reference)
//
#include <hip/hip_runtime.h>

#define HD   64
#define NB   4
#define PROJ 256   // HD * NB columns
#define NPB  32    // nodes per block in proj kernel

__device__ __forceinline__ float bf2f(unsigned short u) {
    union { unsigned int i; float f; } c; c.i = ((unsigned int)u) << 16; return c.f;
}
__device__ __forceinline__ unsigned short f2bf(float f) {
    union { float f; unsigned int i; } c; c.f = f;
    unsigned int r = c.i + 0x7FFF + ((c.i >> 16) & 1);   // round-to-nearest-even
    return (unsigned short)(r >> 16);
}

// xb layout: bf16 xb[n][o*4 + b]  (o = output dim 0..63, b = basis 0..3)
__global__ __launch_bounds__(256) void proj_kernel(
    const float* __restrict__ f, const float* __restrict__ Vl,
    unsigned short* __restrict__ xb, int n_nodes) {
    int c = threadIdx.x;        // column: c = o*4 + b
    int b = c & 3;
    int o = c >> 2;
    float w[HD];
#pragma unroll
    for (int i = 0; i < HD; ++i) w[i] = Vl[((size_t)b * HD + i) * HD + o];

    __shared__ float fs[NPB * HD];
    int n0 = blockIdx.x * NPB;
#pragma unroll
    for (int k = 0; k < (NPB * HD) / 256; ++k) {
        int idx = k * 256 + c;
        int n = n0 + idx / HD;
        fs[idx] = (n < n_nodes) ? f[(size_t)n0 * HD + idx] : 0.f;
    }
    __syncthreads();

    int nmax = n_nodes - n0; if (nmax > NPB) nmax = NPB;
    for (int n = 0; n < nmax; ++n) {
        float acc = 0.f;
#pragma unroll
        for (int i = 0; i < HD; ++i) acc += fs[n * HD + i] * w[i];  // LDS broadcast
        xb[(size_t)(n0 + n) * PROJ + c] = f2bf(acc);
    }
}

__global__ __launch_bounds__(256) void edge_kernel(
    const unsigned short* __restrict__ xb, const float* __restrict__ comp_l,
    const float* __restrict__ norm,
    const int* __restrict__ src, const int* __restrict__ dst,
    const int* __restrict__ etype,
    float* __restrict__ h, int n_edges) {
    int e = blockIdx.x * 4 + (threadIdx.x >> 6);
    if (e >= n_edges) return;
    int lane = threadIdx.x & 63;
    int s = src[e];
    int d = dst[e];
    int r = etype[e];
    float nrm = norm[e];
    float4 cf = *(const float4*)(comp_l + (size_t)r * NB);
    // lane o reads 4 bf16 (8B): xb[s][o*4 .. o*4+3]; wave = 512B contiguous
    ushort4 v = ((const ushort4*)(xb + (size_t)s * PROJ))[lane];
    float m = nrm * (cf.x * bf2f(v.x) + cf.y * bf2f(v.y) +
                     cf.z * bf2f(v.z) + cf.w * bf2f(v.w));
    atomicAdd(h + (size_t)d * HD + lane, m);
}

__global__ __launch_bounds__(256) void finish_kernel(
    const float* __restrict__ h, const float* __restrict__ f,
    const float* __restrict__ bias_l, float* __restrict__ out, int total) {
    int i = blockIdx.x * 256 + threadIdx.x;
    if (i >= total) return;
    float v = h[i] + bias_l[i & (HD - 1)];
    out[i] = fmaxf(v, 0.f) + f[i];
}

extern "C" void kernel_launch(void* const* d_in, const int* in_sizes, int n_in,
                              void* d_out, int out_size, void* d_ws, size_t ws_size,
                              hipStream_t stream) {
    const float* features = (const float*)d_in[0];
    const float* norm     = (const float*)d_in[1];
    const float* V        = (const float*)d_in[2];
    const float* comp     = (const float*)d_in[3];
    const float* bias     = (const float*)d_in[4];
    const int*   src      = (const int*)d_in[5];
    const int*   dst      = (const int*)d_in[6];
    const int*   etype    = (const int*)d_in[7];
    float* out = (float*)d_out;

    int n_nodes = in_sizes[0] / HD;
    int n_edges = in_sizes[5];
    int L       = in_sizes[2] / (NB * HD * HD);   // N_HID
    int l       = L - 1;                          // only the last layer survives
    int comp_stride = in_sizes[3] / L;            // NUM_RELS * NB

    const float* Vl     = V    + (size_t)l * NB * HD * HD;
    const float* comp_l = comp + (size_t)l * comp_stride;
    const float* bias_l = bias + (size_t)l * HD;

    unsigned short* xb = (unsigned short*)d_ws;               // bf16 [n_nodes, 256]
    float* h = (float*)(xb + (size_t)n_nodes * PROJ);         // f32 [n_nodes, 64]

    hipMemsetAsync(h, 0, (size_t)n_nodes * HD * sizeof(float), stream);

    proj_kernel<<<(n_nodes + NPB - 1) / NPB, 256, 0, stream>>>(features, Vl, xb, n_nodes);
    edge_kernel<<<(n_edges + 3) / 4, 256, 0, stream>>>(xb, comp_l, norm, src, dst, etype, h, n_edges);

    int total = n_nodes * HD;
    finish_kernel<<<(total + 255) / 256, 256, 0, stream>>>(h, features, bias_l, out, total);
}

// Round 3
// 305.033 us; speedup vs baseline: 1.1304x; 1.1304x over previous
//
#include <hip/hip_runtime.h>

#define HD   64
#define NB   4
#define PROJ 256   // HD * NB columns
#define NPB  32    // nodes per block in proj kernel
#define SCAN_BLK 1024

__device__ __forceinline__ float bf2f(unsigned short u) {
    union { unsigned int i; float f; } c; c.i = ((unsigned int)u) << 16; return c.f;
}
__device__ __forceinline__ unsigned short f2bf(float f) {
    union { float f; unsigned int i; } c; c.f = f;
    unsigned int r = c.i + 0x7FFF + ((c.i >> 16) & 1);   // round-to-nearest-even
    return (unsigned short)(r >> 16);
}

// xb layout: bf16 xb[n][o*4 + b]  (o = output dim 0..63, b = basis 0..3)
__global__ __launch_bounds__(256) void proj_kernel(
    const float* __restrict__ f, const float* __restrict__ Vl,
    unsigned short* __restrict__ xb, int n_nodes) {
    int c = threadIdx.x;        // column: c = o*4 + b
    int b = c & 3;
    int o = c >> 2;
    float w[HD];
#pragma unroll
    for (int i = 0; i < HD; ++i) w[i] = Vl[((size_t)b * HD + i) * HD + o];

    __shared__ float fs[NPB * HD];
    int n0 = blockIdx.x * NPB;
#pragma unroll
    for (int k = 0; k < (NPB * HD) / 256; ++k) {
        int idx = k * 256 + c;
        int n = n0 + idx / HD;
        fs[idx] = (n < n_nodes) ? f[(size_t)n0 * HD + idx] : 0.f;
    }
    __syncthreads();

    int nmax = n_nodes - n0; if (nmax > NPB) nmax = NPB;
    for (int n = 0; n < nmax; ++n) {
        float acc = 0.f;
#pragma unroll
        for (int i = 0; i < HD; ++i) acc += fs[n * HD + i] * w[i];
        xb[(size_t)(n0 + n) * PROJ + c] = f2bf(acc);
    }
}

// ---- CSR build: histogram -> exclusive scan -> scatter ----

__global__ __launch_bounds__(256) void hist_kernel(
    const int* __restrict__ dst, int* __restrict__ cnt, int n_edges) {
    int e = blockIdx.x * 256 + threadIdx.x;
    if (e < n_edges) atomicAdd(&cnt[dst[e]], 1);
}

// per-block exclusive scan over SCAN_BLK elems; emits block sums
__global__ __launch_bounds__(256) void scan_a_kernel(
    const int* __restrict__ cnt, int* __restrict__ offs,
    int* __restrict__ bsum, int n) {
    __shared__ int sd[256];
    int t = threadIdx.x;
    int base = blockIdx.x * SCAN_BLK + t * 4;
    int v[4];
#pragma unroll
    for (int j = 0; j < 4; ++j) v[j] = (base + j < n) ? cnt[base + j] : 0;
    int s = v[0] + v[1] + v[2] + v[3];
    sd[t] = s; __syncthreads();
    for (int off = 1; off < 256; off <<= 1) {
        int x = (t >= off) ? sd[t - off] : 0;
        __syncthreads();
        sd[t] += x;
        __syncthreads();
    }
    int excl = sd[t] - s;
    if (t == 255) bsum[blockIdx.x] = sd[t];
    int run = excl;
#pragma unroll
    for (int j = 0; j < 4; ++j) {
        if (base + j < n) offs[base + j] = run;
        run += v[j];
    }
}

// single block scans the (<=256) block sums in place -> exclusive
__global__ __launch_bounds__(256) void scan_b_kernel(int* __restrict__ bsum, int nblk) {
    __shared__ int sd[256];
    int t = threadIdx.x;
    int s = (t < nblk) ? bsum[t] : 0;
    sd[t] = s; __syncthreads();
    for (int off = 1; off < 256; off <<= 1) {
        int x = (t >= off) ? sd[t - off] : 0;
        __syncthreads();
        sd[t] += x;
        __syncthreads();
    }
    if (t < nblk) bsum[t] = sd[t] - s;
}

__global__ __launch_bounds__(256) void scan_c_kernel(
    int* __restrict__ offs, int* __restrict__ cursor,
    const int* __restrict__ bsum, int n) {
    int i = blockIdx.x * 256 + threadIdx.x;
    if (i < n) {
        int v = offs[i] + bsum[i / SCAN_BLK];
        offs[i] = v;
        cursor[i] = v;
    }
}

// pack {src | etype<<20, norm_bits} into 8B record at sorted position
__global__ __launch_bounds__(256) void scatter_kernel(
    const int* __restrict__ src, const int* __restrict__ dst,
    const int* __restrict__ etype, const float* __restrict__ norm,
    int* __restrict__ cursor, uint2* __restrict__ rec, int n_edges) {
    int e = blockIdx.x * 256 + threadIdx.x;
    if (e >= n_edges) return;
    int d = dst[e];
    int pos = atomicAdd(&cursor[d], 1);
    uint2 rr;
    rr.x = (unsigned)src[e] | ((unsigned)etype[e] << 20);
    rr.y = __float_as_uint(norm[e]);
    rec[pos] = rr;
}

// segmented sum: one wave per dst node; fused bias+relu+skip epilogue
__global__ __launch_bounds__(256) void seg_kernel(
    const uint2* __restrict__ rec, const int* __restrict__ offs,
    const int* __restrict__ cnt, const unsigned short* __restrict__ xb,
    const float* __restrict__ comp_l, const float* __restrict__ bias_l,
    const float* __restrict__ f, float* __restrict__ out, int n_nodes) {
    int d = blockIdx.x * 4 + (threadIdx.x >> 6);
    if (d >= n_nodes) return;
    int lane = threadIdx.x & 63;
    int start = offs[d];
    int deg = cnt[d];
    const uint2* r = rec + start;
    float acc = 0.f;
    int k = 0;
    for (; k + 4 <= deg; k += 4) {
        uint2 q0 = r[k], q1 = r[k+1], q2 = r[k+2], q3 = r[k+3];
        ushort4 v0 = ((const ushort4*)(xb + (size_t)(q0.x & 0xFFFFF) * PROJ))[lane];
        ushort4 v1 = ((const ushort4*)(xb + (size_t)(q1.x & 0xFFFFF) * PROJ))[lane];
        ushort4 v2 = ((const ushort4*)(xb + (size_t)(q2.x & 0xFFFFF) * PROJ))[lane];
        ushort4 v3 = ((const ushort4*)(xb + (size_t)(q3.x & 0xFFFFF) * PROJ))[lane];
        float4 c0 = *(const float4*)(comp_l + ((q0.x >> 20) & 31) * NB);
        float4 c1 = *(const float4*)(comp_l + ((q1.x >> 20) & 31) * NB);
        float4 c2 = *(const float4*)(comp_l + ((q2.x >> 20) & 31) * NB);
        float4 c3 = *(const float4*)(comp_l + ((q3.x >> 20) & 31) * NB);
        acc += __uint_as_float(q0.y) * (c0.x*bf2f(v0.x) + c0.y*bf2f(v0.y) + c0.z*bf2f(v0.z) + c0.w*bf2f(v0.w));
        acc += __uint_as_float(q1.y) * (c1.x*bf2f(v1.x) + c1.y*bf2f(v1.y) + c1.z*bf2f(v1.z) + c1.w*bf2f(v1.w));
        acc += __uint_as_float(q2.y) * (c2.x*bf2f(v2.x) + c2.y*bf2f(v2.y) + c2.z*bf2f(v2.z) + c2.w*bf2f(v2.w));
        acc += __uint_as_float(q3.y) * (c3.x*bf2f(v3.x) + c3.y*bf2f(v3.y) + c3.z*bf2f(v3.z) + c3.w*bf2f(v3.w));
    }
    for (; k < deg; ++k) {
        uint2 q = r[k];
        ushort4 v = ((const ushort4*)(xb + (size_t)(q.x & 0xFFFFF) * PROJ))[lane];
        float4 c = *(const float4*)(comp_l + ((q.x >> 20) & 31) * NB);
        acc += __uint_as_float(q.y) * (c.x*bf2f(v.x) + c.y*bf2f(v.y) + c.z*bf2f(v.z) + c.w*bf2f(v.w));
    }
    float hv = acc + bias_l[lane];
    size_t o = (size_t)d * HD + lane;
    out[o] = fmaxf(hv, 0.f) + f[o];
}

extern "C" void kernel_launch(void* const* d_in, const int* in_sizes, int n_in,
                              void* d_out, int out_size, void* d_ws, size_t ws_size,
                              hipStream_t stream) {
    const float* features = (const float*)d_in[0];
    const float* norm     = (const float*)d_in[1];
    const float* V        = (const float*)d_in[2];
    const float* comp     = (const float*)d_in[3];
    const float* bias     = (const float*)d_in[4];
    const int*   src      = (const int*)d_in[5];
    const int*   dst      = (const int*)d_in[6];
    const int*   etype    = (const int*)d_in[7];
    float* out = (float*)d_out;

    int n_nodes = in_sizes[0] / HD;
    int n_edges = in_sizes[5];
    int L       = in_sizes[2] / (NB * HD * HD);   // N_HID
    int l       = L - 1;                          // only the last layer survives
    int comp_stride = in_sizes[3] / L;            // NUM_RELS * NB

    const float* Vl     = V    + (size_t)l * NB * HD * HD;
    const float* comp_l = comp + (size_t)l * comp_stride;
    const float* bias_l = bias + (size_t)l * HD;

    // workspace carve-up
    char* ws = (char*)d_ws;
    unsigned short* xb = (unsigned short*)ws;                 // bf16 [n_nodes, 256]
    size_t off = (size_t)n_nodes * PROJ * sizeof(unsigned short);
    int* cnt    = (int*)(ws + off);  off += (size_t)n_nodes * sizeof(int);
    int* offs   = (int*)(ws + off);  off += (size_t)n_nodes * sizeof(int);
    int* cursor = (int*)(ws + off);  off += (size_t)n_nodes * sizeof(int);
    int* bsum   = (int*)(ws + off);  off += 1024 * sizeof(int);
    off = (off + 7) & ~(size_t)7;                             // align 8B
    uint2* rec  = (uint2*)(ws + off);                         // [n_edges]

    hipMemsetAsync(cnt, 0, (size_t)n_nodes * sizeof(int), stream);

    proj_kernel<<<(n_nodes + NPB - 1) / NPB, 256, 0, stream>>>(features, Vl, xb, n_nodes);

    int eblocks = (n_edges + 255) / 256;
    hist_kernel<<<eblocks, 256, 0, stream>>>(dst, cnt, n_edges);

    int nblk = (n_nodes + SCAN_BLK - 1) / SCAN_BLK;           // must be <= 256
    scan_a_kernel<<<nblk, 256, 0, stream>>>(cnt, offs, bsum, n_nodes);
    scan_b_kernel<<<1, 256, 0, stream>>>(bsum, nblk);
    scan_c_kernel<<<(n_nodes + 255) / 256, 256, 0, stream>>>(offs, cursor, bsum, n_nodes);

    scatter_kernel<<<eblocks, 256, 0, stream>>>(src, dst, etype, norm, cursor, rec, n_edges);

    seg_kernel<<<(n_nodes + 3) / 4, 256, 0, stream>>>(rec, offs, cnt, xb, comp_l,
                                                      bias_l, features, out, n_nodes);
}

// Round 4
// 239.225 us; speedup vs baseline: 1.4414x; 1.2751x over previous
//
#include <hip/hip_runtime.h>

#define HD   64
#define NB   4
#define PROJ 256   // HD * NB columns
#define SCAN_BLK 1024

typedef __attribute__((ext_vector_type(8))) short bf16x8;
typedef __attribute__((ext_vector_type(4))) float f32x4;

__device__ __forceinline__ float bf2f(unsigned short u) {
    union { unsigned int i; float f; } c; c.i = ((unsigned int)u) << 16; return c.f;
}
__device__ __forceinline__ unsigned short f2bf(float f) {
    union { float f; unsigned int i; } c; c.f = f;
    unsigned int r = c.i + 0x7FFF + ((c.i >> 16) & 1);   // round-to-nearest-even
    return (unsigned short)(r >> 16);
}

// ---- W pre-pack: A-operand fragments for the swapped MFMA ----
// wpack[((ct*2+ks)*64 + lane)*8 + j] = W[k][c], k = ks*32 + ((lane>>4)&3)*8 + j,
// c = ct*16 + (lane&15);  W[k][c] = Vl[b][k][o] with o=c>>2, b=c&3.
__global__ __launch_bounds__(256) void wpack_kernel(
    const float* __restrict__ Vl, unsigned short* __restrict__ wpack) {
    int t = threadIdx.x;
#pragma unroll
    for (int i = 0; i < 8; ++i) {
        int s = t + i * 256;            // 0..2047 lane-slots
        int lane = s & 63;
        int ksct = s >> 6;
        int ks = ksct & 1, ct = ksct >> 1;
        int c = ct * 16 + (lane & 15);
        int o = c >> 2, b = c & 3;
        unsigned int w[4];
#pragma unroll
        for (int j = 0; j < 4; ++j) {
            int k0 = ks * 32 + ((lane >> 4) & 3) * 8 + 2 * j;
            unsigned short lo = f2bf(Vl[((size_t)b * HD + k0) * HD + o]);
            unsigned short hi = f2bf(Vl[((size_t)b * HD + k0 + 1) * HD + o]);
            w[j] = (unsigned)lo | ((unsigned)hi << 16);
        }
        uint4 st = make_uint4(w[0], w[1], w[2], w[3]);
        *(uint4*)(wpack + (size_t)s * 8) = st;
    }
}

// ---- MFMA projection: xb[n][c] (bf16) = sum_k f[n][k] * W[k][c] ----
#define FS_STRIDE 72   // padded bf16 row stride: 2-way bank aliasing only
__global__ __launch_bounds__(256, 4) void proj_mfma_kernel(
    const float* __restrict__ f, const unsigned short* __restrict__ wpack,
    unsigned short* __restrict__ xb, int n_nodes) {
    __shared__ unsigned short fs[64 * FS_STRIDE];
    int t = threadIdx.x;
    int lane = t & 63;
    int wt = t >> 6;                 // wave id: nodes [n0+wt*16, +16)
    int n0 = blockIdx.x * 64;

    // stage 64 node rows as bf16 (coalesced float4 loads, cvt once)
#pragma unroll
    for (int i = 0; i < 4; ++i) {
        int idx = t + i * 256;               // 0..1023 float4 slots
        int node = idx >> 4;                 // 16 float4 per row
        int kg = idx & 15;
        unsigned int lo = 0, hi = 0;
        if (n0 + node < n_nodes) {
            float4 v = *(const float4*)(f + ((size_t)(n0 + node) * HD + kg * 4));
            lo = (unsigned)f2bf(v.x) | ((unsigned)f2bf(v.y) << 16);
            hi = (unsigned)f2bf(v.z) | ((unsigned)f2bf(v.w) << 16);
        }
        *(uint2*)(fs + node * FS_STRIDE + kg * 4) = make_uint2(lo, hi);
    }
    __syncthreads();

    // B-fragments: 16 nodes x K=32 per ks, one ds_read_b128 each
    bf16x8 bfr[2];
#pragma unroll
    for (int ks = 0; ks < 2; ++ks) {
        int off = (wt * 16 + (lane & 15)) * FS_STRIDE + ks * 32 + ((lane >> 4) & 3) * 8;
        bfr[ks] = *reinterpret_cast<const bf16x8*>(&fs[off]);
    }

    f32x4 acc[16];
#pragma unroll
    for (int ct = 0; ct < 16; ++ct) acc[ct] = (f32x4){0.f, 0.f, 0.f, 0.f};

#pragma unroll
    for (int ct = 0; ct < 16; ++ct) {
#pragma unroll
        for (int ks = 0; ks < 2; ++ks) {
            bf16x8 a = *reinterpret_cast<const bf16x8*>(
                wpack + ((size_t)(ct * 2 + ks) * 64 + lane) * 8);
            acc[ct] = __builtin_amdgcn_mfma_f32_16x16x32_bf16(a, bfr[ks], acc[ct], 0, 0, 0);
        }
    }

    // D layout: N-side (node) = lane&15, M-side (col) = (lane>>4)*4 + reg
    int node = n0 + wt * 16 + (lane & 15);
    if (node < n_nodes) {
#pragma unroll
        for (int ct = 0; ct < 16; ++ct) {
            int c0 = ct * 16 + ((lane >> 4) & 3) * 4;
            unsigned int lo = (unsigned)f2bf(acc[ct][0]) | ((unsigned)f2bf(acc[ct][1]) << 16);
            unsigned int hi = (unsigned)f2bf(acc[ct][2]) | ((unsigned)f2bf(acc[ct][3]) << 16);
            *(uint2*)(xb + (size_t)node * PROJ + c0) = make_uint2(lo, hi);
        }
    }
}

// ---- CSR build: histogram -> exclusive scan -> scatter ----

__global__ __launch_bounds__(256) void hist_kernel(
    const int* __restrict__ dst, int* __restrict__ cnt, int n_edges) {
    int e = blockIdx.x * 256 + threadIdx.x;
    if (e < n_edges) atomicAdd(&cnt[dst[e]], 1);
}

__global__ __launch_bounds__(256) void scan_a_kernel(
    const int* __restrict__ cnt, int* __restrict__ offs,
    int* __restrict__ bsum, int n) {
    __shared__ int sd[256];
    int t = threadIdx.x;
    int base = blockIdx.x * SCAN_BLK + t * 4;
    int v[4];
#pragma unroll
    for (int j = 0; j < 4; ++j) v[j] = (base + j < n) ? cnt[base + j] : 0;
    int s = v[0] + v[1] + v[2] + v[3];
    sd[t] = s; __syncthreads();
    for (int off = 1; off < 256; off <<= 1) {
        int x = (t >= off) ? sd[t - off] : 0;
        __syncthreads();
        sd[t] += x;
        __syncthreads();
    }
    int excl = sd[t] - s;
    if (t == 255) bsum[blockIdx.x] = sd[t];
    int run = excl;
#pragma unroll
    for (int j = 0; j < 4; ++j) {
        if (base + j < n) offs[base + j] = run;
        run += v[j];
    }
}

__global__ __launch_bounds__(256) void scan_b_kernel(int* __restrict__ bsum, int nblk) {
    __shared__ int sd[256];
    int t = threadIdx.x;
    int s = (t < nblk) ? bsum[t] : 0;
    sd[t] = s; __syncthreads();
    for (int off = 1; off < 256; off <<= 1) {
        int x = (t >= off) ? sd[t - off] : 0;
        __syncthreads();
        sd[t] += x;
        __syncthreads();
    }
    if (t < nblk) bsum[t] = sd[t] - s;
}

__global__ __launch_bounds__(256) void scan_c_kernel(
    int* __restrict__ offs, int* __restrict__ cursor,
    const int* __restrict__ bsum, int n) {
    int i = blockIdx.x * 256 + threadIdx.x;
    if (i < n) {
        int v = offs[i] + bsum[i / SCAN_BLK];
        offs[i] = v;
        cursor[i] = v;
    }
}

__global__ __launch_bounds__(256) void scatter_kernel(
    const int* __restrict__ src, const int* __restrict__ dst,
    const int* __restrict__ etype, const float* __restrict__ norm,
    int* __restrict__ cursor, uint2* __restrict__ rec, int n_edges) {
    int e = blockIdx.x * 256 + threadIdx.x;
    if (e >= n_edges) return;
    int d = dst[e];
    int pos = atomicAdd(&cursor[d], 1);
    uint2 rr;
    rr.x = (unsigned)src[e] | ((unsigned)etype[e] << 20);
    rr.y = __float_as_uint(norm[e]);
    rec[pos] = rr;
}

// segmented sum: one wave per dst node; fused bias+relu+skip epilogue
__global__ __launch_bounds__(256) void seg_kernel(
    const uint2* __restrict__ rec, const int* __restrict__ offs,
    const int* __restrict__ cnt, const unsigned short* __restrict__ xb,
    const float* __restrict__ comp_l, const float* __restrict__ bias_l,
    const float* __restrict__ f, float* __restrict__ out, int n_nodes) {
    int d = blockIdx.x * 4 + (threadIdx.x >> 6);
    if (d >= n_nodes) return;
    int lane = threadIdx.x & 63;
    int start = offs[d];
    int deg = cnt[d];
    const uint2* r = rec + start;
    float acc = 0.f;
    int k = 0;
    for (; k + 4 <= deg; k += 4) {
        uint2 q0 = r[k], q1 = r[k+1], q2 = r[k+2], q3 = r[k+3];
        ushort4 v0 = ((const ushort4*)(xb + (size_t)(q0.x & 0xFFFFF) * PROJ))[lane];
        ushort4 v1 = ((const ushort4*)(xb + (size_t)(q1.x & 0xFFFFF) * PROJ))[lane];
        ushort4 v2 = ((const ushort4*)(xb + (size_t)(q2.x & 0xFFFFF) * PROJ))[lane];
        ushort4 v3 = ((const ushort4*)(xb + (size_t)(q3.x & 0xFFFFF) * PROJ))[lane];
        float4 c0 = *(const float4*)(comp_l + ((q0.x >> 20) & 31) * NB);
        float4 c1 = *(const float4*)(comp_l + ((q1.x >> 20) & 31) * NB);
        float4 c2 = *(const float4*)(comp_l + ((q2.x >> 20) & 31) * NB);
        float4 c3 = *(const float4*)(comp_l + ((q3.x >> 20) & 31) * NB);
        acc += __uint_as_float(q0.y) * (c0.x*bf2f(v0.x) + c0.y*bf2f(v0.y) + c0.z*bf2f(v0.z) + c0.w*bf2f(v0.w));
        acc += __uint_as_float(q1.y) * (c1.x*bf2f(v1.x) + c1.y*bf2f(v1.y) + c1.z*bf2f(v1.z) + c1.w*bf2f(v1.w));
        acc += __uint_as_float(q2.y) * (c2.x*bf2f(v2.x) + c2.y*bf2f(v2.y) + c2.z*bf2f(v2.z) + c2.w*bf2f(v2.w));
        acc += __uint_as_float(q3.y) * (c3.x*bf2f(v3.x) + c3.y*bf2f(v3.y) + c3.z*bf2f(v3.z) + c3.w*bf2f(v3.w));
    }
    for (; k < deg; ++k) {
        uint2 q = r[k];
        ushort4 v = ((const ushort4*)(xb + (size_t)(q.x & 0xFFFFF) * PROJ))[lane];
        float4 c = *(const float4*)(comp_l + ((q.x >> 20) & 31) * NB);
        acc += __uint_as_float(q.y) * (c.x*bf2f(v.x) + c.y*bf2f(v.y) + c.z*bf2f(v.z) + c.w*bf2f(v.w));
    }
    float hv = acc + bias_l[lane];
    size_t o = (size_t)d * HD + lane;
    out[o] = fmaxf(hv, 0.f) + f[o];
}

extern "C" void kernel_launch(void* const* d_in, const int* in_sizes, int n_in,
                              void* d_out, int out_size, void* d_ws, size_t ws_size,
                              hipStream_t stream) {
    const float* features = (const float*)d_in[0];
    const float* norm     = (const float*)d_in[1];
    const float* V        = (const float*)d_in[2];
    const float* comp     = (const float*)d_in[3];
    const float* bias     = (const float*)d_in[4];
    const int*   src      = (const int*)d_in[5];
    const int*   dst      = (const int*)d_in[6];
    const int*   etype    = (const int*)d_in[7];
    float* out = (float*)d_out;

    int n_nodes = in_sizes[0] / HD;
    int n_edges = in_sizes[5];
    int L       = in_sizes[2] / (NB * HD * HD);   // N_HID
    int l       = L - 1;                          // only the last layer survives
    int comp_stride = in_sizes[3] / L;            // NUM_RELS * NB

    const float* Vl     = V    + (size_t)l * NB * HD * HD;
    const float* comp_l = comp + (size_t)l * comp_stride;
    const float* bias_l = bias + (size_t)l * HD;

    // workspace carve-up
    char* ws = (char*)d_ws;
    unsigned short* xb = (unsigned short*)ws;                 // bf16 [n_nodes, 256]
    size_t off = (size_t)n_nodes * PROJ * sizeof(unsigned short);
    int* cnt    = (int*)(ws + off);  off += (size_t)n_nodes * sizeof(int);
    int* offs   = (int*)(ws + off);  off += (size_t)n_nodes * sizeof(int);
    int* cursor = (int*)(ws + off);  off += (size_t)n_nodes * sizeof(int);
    int* bsum   = (int*)(ws + off);  off += 1024 * sizeof(int);
    unsigned short* wpack = (unsigned short*)(ws + off); off += 2048 * 8 * sizeof(unsigned short);
    off = (off + 7) & ~(size_t)7;                             // align 8B
    uint2* rec  = (uint2*)(ws + off);                         // [n_edges]

    hipMemsetAsync(cnt, 0, (size_t)n_nodes * sizeof(int), stream);

    wpack_kernel<<<1, 256, 0, stream>>>(Vl, wpack);
    proj_mfma_kernel<<<(n_nodes + 63) / 64, 256, 0, stream>>>(features, wpack, xb, n_nodes);

    int eblocks = (n_edges + 255) / 256;
    hist_kernel<<<eblocks, 256, 0, stream>>>(dst, cnt, n_edges);

    int nblk = (n_nodes + SCAN_BLK - 1) / SCAN_BLK;           // <= 256
    scan_a_kernel<<<nblk, 256, 0, stream>>>(cnt, offs, bsum, n_nodes);
    scan_b_kernel<<<1, 256, 0, stream>>>(bsum, nblk);
    scan_c_kernel<<<(n_nodes + 255) / 256, 256, 0, stream>>>(offs, cursor, bsum, n_nodes);

    scatter_kernel<<<eblocks, 256, 0, stream>>>(src, dst, etype, norm, cursor, rec, n_edges);

    seg_kernel<<<(n_nodes + 3) / 4, 256, 0, stream>>>(rec, offs, cnt, xb, comp_l,
                                                      bias_l, features, out, n_nodes);
}